// Round 1
// baseline (1548.660 us; speedup 1.0000x reference)
//
#include <hip/hip_runtime.h>
#include <hip/hip_bf16.h>

#define EMB_D 100
#define HID 64
#define G4 256
#define BATCH 128
#define SEQ 1024

__device__ __forceinline__ float sigf(float x) { return 1.0f / (1.0f + __expf(-x)); }
__device__ __forceinline__ float tanh_fast(float x) {
  float t = __expf(-2.0f * fabsf(x));
  float r = (1.0f - t) / (1.0f + t);
  return copysignf(r, x);
}

// --- prep: combined biases + transposed Wih0 (for coalesced access) ---
__global__ void prep_kernel(const float* __restrict__ Wih0,
                            const float* __restrict__ bih0, const float* __restrict__ bhh0,
                            const float* __restrict__ bih1, const float* __restrict__ bhh1,
                            float* __restrict__ Wih0T, float* __restrict__ b0c,
                            float* __restrict__ b1c) {
  int g = threadIdx.x;
  b0c[g] = bih0[g] + bhh0[g];
  b1c[g] = bih1[g] + bhh1[g];
  for (int d = 0; d < EMB_D; ++d) Wih0T[d * G4 + g] = Wih0[g * EMB_D + d];
}

// --- xw0[token][gate] = emb[x[token]] . Wih0[gate] + b0 ---
// thread g owns gate g; Wih0T column g lives in 100 VGPRs; emb rows arrive
// via wave-uniform scalar loads (idx is uniform -> s_load path).
__global__ __launch_bounds__(256) void xw0_kernel(
    const int* __restrict__ x, const float* __restrict__ emb,
    const float* __restrict__ Wih0T, const float* __restrict__ b0c,
    float* __restrict__ xw0) {
  int g = threadIdx.x;
  long t0 = (long)blockIdx.x * 32;
  float w[EMB_D];
  #pragma unroll
  for (int d = 0; d < EMB_D; ++d) w[d] = Wih0T[d * G4 + g];
  float bb = b0c[g];
  for (int tk = 0; tk < 32; ++tk) {
    int idx = x[t0 + tk];
    const float* er = emb + (long)idx * EMB_D;
    float a0 = bb, a1 = 0.f, a2 = 0.f, a3 = 0.f;
    #pragma unroll
    for (int d = 0; d < EMB_D; d += 4) {
      a0 = fmaf(w[d],     er[d],     a0);
      a1 = fmaf(w[d + 1], er[d + 1], a1);
      a2 = fmaf(w[d + 2], er[d + 2], a2);
      a3 = fmaf(w[d + 3], er[d + 3], a3);
    }
    xw0[(t0 + tk) * G4 + g] = (a0 + a1) + (a2 + a3);
  }
}

// --- fused 2-layer recurrence + classifier head ---
// 128 blocks (one batch row), 256 threads (one gate each).
// Pipeline: iter t computes layer0 step t AND layer1 step t-1 (both read
// h0_{t-1}); threads 0..63 update (h0,c0), threads 64..127 update (h1,c1).
__global__ __launch_bounds__(256, 1) void lstm_fused_kernel(
    const float* __restrict__ xw0,
    const float* __restrict__ Whh0, const float* __restrict__ Wih1,
    const float* __restrict__ Whh1, const float* __restrict__ b1c,
    const float* __restrict__ W1, const float* __restrict__ clsb1,
    const float* __restrict__ W2, const float* __restrict__ clsb2,
    float* __restrict__ out) {
  int b = blockIdx.x;
  int g = threadIdx.x;

  float whh0[HID], wih1[HID], whh1[HID];
  {
    const float4* p0 = (const float4*)(Whh0 + g * HID);
    const float4* p1 = (const float4*)(Wih1 + g * HID);
    const float4* p2 = (const float4*)(Whh1 + g * HID);
    #pragma unroll
    for (int c = 0; c < 16; ++c) {
      float4 v0 = p0[c], v1 = p1[c], v2 = p2[c];
      whh0[4*c] = v0.x; whh0[4*c+1] = v0.y; whh0[4*c+2] = v0.z; whh0[4*c+3] = v0.w;
      wih1[4*c] = v1.x; wih1[4*c+1] = v1.y; wih1[4*c+2] = v1.z; wih1[4*c+3] = v1.w;
      whh1[4*c] = v2.x; whh1[4*c+1] = v2.y; whh1[4*c+2] = v2.z; whh1[4*c+3] = v2.w;
    }
  }

  __shared__ float4 h0s4[16];
  __shared__ float4 h1s4[16];
  __shared__ float gs0[G4];
  __shared__ float gs1[G4];
  __shared__ float zs[HID];
  float* h0f = (float*)h0s4;
  float* h1f = (float*)h1s4;
  if (g < HID) { h0f[g] = 0.f; h1f[g] = 0.f; }
  float c0 = 0.f, c1 = 0.f;
  float bias1 = b1c[g];
  const float* xr = xw0 + (long)b * SEQ * G4;
  float xwA = xr[g];          // xw0 for t=0
  float xwB = xr[G4 + g];     // xw0 for t=1
  __syncthreads();

  for (int t = 0; t < SEQ; ++t) {
    int tn = (t + 2 < SEQ) ? (t + 2) : (SEQ - 1);
    float xwC = xr[(long)tn * G4 + g];   // distance-2 prefetch

    float a0 = xwA, a1 = 0.f, a2 = 0.f, a3 = 0.f;     // layer0 gates
    float d0 = bias1, d1 = 0.f, d2 = 0.f, d3 = 0.f;   // layer1 gates (step t-1)
    #pragma unroll
    for (int c = 0; c < 16; ++c) {
      float4 hv = h0s4[c];
      a0 = fmaf(hv.x, whh0[4*c],   a0);
      a1 = fmaf(hv.y, whh0[4*c+1], a1);
      a2 = fmaf(hv.z, whh0[4*c+2], a2);
      a3 = fmaf(hv.w, whh0[4*c+3], a3);
      d0 = fmaf(hv.x, wih1[4*c],   d0);
      d1 = fmaf(hv.y, wih1[4*c+1], d1);
      d2 = fmaf(hv.z, wih1[4*c+2], d2);
      d3 = fmaf(hv.w, wih1[4*c+3], d3);
    }
    #pragma unroll
    for (int c = 0; c < 16; ++c) {
      float4 hv = h1s4[c];
      d0 = fmaf(hv.x, whh1[4*c],   d0);
      d1 = fmaf(hv.y, whh1[4*c+1], d1);
      d2 = fmaf(hv.z, whh1[4*c+2], d2);
      d3 = fmaf(hv.w, whh1[4*c+3], d3);
    }
    gs0[g] = (a0 + a1) + (a2 + a3);
    gs1[g] = (d0 + d1) + (d2 + d3);
    __syncthreads();
    if (g < HID) {
      float i_ = gs0[g], f_ = gs0[g + 64], gg = gs0[g + 128], o_ = gs0[g + 192];
      c0 = sigf(f_) * c0 + sigf(i_) * tanh_fast(gg);
      h0f[g] = sigf(o_) * tanh_fast(c0);
    } else if (g < 2 * HID) {
      if (t > 0) {
        int j = g - HID;
        float i_ = gs1[j], f_ = gs1[j + 64], gg = gs1[j + 128], o_ = gs1[j + 192];
        c1 = sigf(f_) * c1 + sigf(i_) * tanh_fast(gg);
        h1f[j] = sigf(o_) * tanh_fast(c1);
      }
    }
    __syncthreads();
    xwA = xwB; xwB = xwC;
  }

  // final layer-1 step (t = SEQ-1): h0s holds h0_{1023}, h1s holds h1_{1022}
  {
    float d0 = bias1, d1 = 0.f, d2 = 0.f, d3 = 0.f;
    #pragma unroll
    for (int c = 0; c < 16; ++c) {
      float4 hv = h0s4[c];
      d0 = fmaf(hv.x, wih1[4*c],   d0);
      d1 = fmaf(hv.y, wih1[4*c+1], d1);
      d2 = fmaf(hv.z, wih1[4*c+2], d2);
      d3 = fmaf(hv.w, wih1[4*c+3], d3);
    }
    #pragma unroll
    for (int c = 0; c < 16; ++c) {
      float4 hv = h1s4[c];
      d0 = fmaf(hv.x, whh1[4*c],   d0);
      d1 = fmaf(hv.y, whh1[4*c+1], d1);
      d2 = fmaf(hv.z, whh1[4*c+2], d2);
      d3 = fmaf(hv.w, whh1[4*c+3], d3);
    }
    gs1[g] = (d0 + d1) + (d2 + d3);
    __syncthreads();
    if (g >= HID && g < 2 * HID) {
      int j = g - HID;
      float i_ = gs1[j], f_ = gs1[j + 64], gg = gs1[j + 128], o_ = gs1[j + 192];
      c1 = sigf(f_) * c1 + sigf(i_) * tanh_fast(gg);
      h1f[j] = sigf(o_) * tanh_fast(c1);
    }
    __syncthreads();
  }

  // classifier: z = relu(h1 @ W1.T + b1); out = sigmoid(z . W2 + b2)
  if (g < HID) {
    const float4* w1p = (const float4*)(W1 + g * HID);
    float z0 = clsb1[g], z1 = 0.f, z2 = 0.f, z3 = 0.f;
    #pragma unroll
    for (int c = 0; c < 16; ++c) {
      float4 wv = w1p[c];
      float4 hv = h1s4[c];
      z0 = fmaf(hv.x, wv.x, z0);
      z1 = fmaf(hv.y, wv.y, z1);
      z2 = fmaf(hv.z, wv.z, z2);
      z3 = fmaf(hv.w, wv.w, z3);
    }
    float z = (z0 + z1) + (z2 + z3);
    z = fmaxf(z, 0.f);
    zs[g] = z * W2[g];
  }
  __syncthreads();
  if (g == 0) {
    float s = clsb2[0];
    #pragma unroll
    for (int k = 0; k < HID; ++k) s += zs[k];
    out[b] = sigf(s);
  }
}

extern "C" void kernel_launch(void* const* d_in, const int* in_sizes, int n_in,
                              void* d_out, int out_size, void* d_ws, size_t ws_size,
                              hipStream_t stream) {
  const int*   x    = (const int*)d_in[0];
  const float* emb  = (const float*)d_in[1];
  const float* Wih0 = (const float*)d_in[2];
  const float* Whh0 = (const float*)d_in[3];
  const float* bih0 = (const float*)d_in[4];
  const float* bhh0 = (const float*)d_in[5];
  const float* Wih1 = (const float*)d_in[6];
  const float* Whh1 = (const float*)d_in[7];
  const float* bih1 = (const float*)d_in[8];
  const float* bhh1 = (const float*)d_in[9];
  const float* W1   = (const float*)d_in[10];
  const float* b1   = (const float*)d_in[11];
  const float* W2   = (const float*)d_in[12];
  const float* b2   = (const float*)d_in[13];
  float* out = (float*)d_out;

  char* ws = (char*)d_ws;
  const size_t XW0_BYTES = (size_t)BATCH * SEQ * G4 * sizeof(float);  // 134217728
  float* xw0   = (float*)ws;
  float* Wih0T = (float*)(ws + XW0_BYTES);
  float* b0c   = (float*)(ws + XW0_BYTES + EMB_D * G4 * sizeof(float));
  float* b1c   = (float*)(ws + XW0_BYTES + EMB_D * G4 * sizeof(float) + G4 * sizeof(float));

  prep_kernel<<<1, 256, 0, stream>>>(Wih0, bih0, bhh0, bih1, bhh1, Wih0T, b0c, b1c);
  xw0_kernel<<<(BATCH * SEQ) / 32, 256, 0, stream>>>(x, emb, Wih0T, b0c, xw0);
  lstm_fused_kernel<<<BATCH, 256, 0, stream>>>(xw0, Whh0, Wih1, Whh1, b1c,
                                               W1, b1, W2, b2, out);
}

// Round 2
// 1058.588 us; speedup vs baseline: 1.4629x; 1.4629x over previous
//
#include <hip/hip_runtime.h>
#include <hip/hip_bf16.h>

#define EMB_D 100
#define HID 64
#define G4 256
#define BATCH 128
#define SEQ 1024
#define TOK 16

__device__ __forceinline__ float sigf(float x) { return 1.0f / (1.0f + __expf(-x)); }
__device__ __forceinline__ float tanh_fast(float x) {
  float t = __expf(-2.0f * fabsf(x));
  float r = (1.0f - t) / (1.0f + t);
  return copysignf(r, x);
}

// --- prep: combined biases + transposed Wih0 (for coalesced access) ---
__global__ void prep_kernel(const float* __restrict__ Wih0,
                            const float* __restrict__ bih0, const float* __restrict__ bhh0,
                            const float* __restrict__ bih1, const float* __restrict__ bhh1,
                            float* __restrict__ Wih0T, float* __restrict__ b0c,
                            float* __restrict__ b1c) {
  int g = threadIdx.x;
  b0c[g] = bih0[g] + bhh0[g];
  b1c[g] = bih1[g] + bhh1[g];
  for (int d = 0; d < EMB_D; ++d) Wih0T[d * G4 + g] = Wih0[g * EMB_D + d];
}

// --- xw0[token][gate] = emb[x[token]] . Wih0[gate] + b0 ---
// 16 tokens per block; embedding rows staged in LDS via coalesced loads,
// then broadcast-read. Thread g holds Wih0 column g in 100 VGPRs.
__global__ __launch_bounds__(256) void xw0_kernel(
    const int* __restrict__ x, const float* __restrict__ emb,
    const float* __restrict__ Wih0T, const float* __restrict__ b0c,
    float* __restrict__ xw0) {
  __shared__ int sidx[TOK];
  __shared__ float erow[TOK][EMB_D];
  int g = threadIdx.x;
  long t0 = (long)blockIdx.x * TOK;

  if (g < TOK) sidx[g] = x[t0 + g];
  __syncthreads();
  for (int i = g; i < TOK * EMB_D; i += 256) {
    int tok = i / EMB_D;
    int d = i - tok * EMB_D;
    erow[tok][d] = emb[(long)sidx[tok] * EMB_D + d];
  }

  float w[EMB_D];
  #pragma unroll
  for (int d = 0; d < EMB_D; ++d) w[d] = Wih0T[d * G4 + g];
  float bb = b0c[g];
  __syncthreads();

  for (int tok = 0; tok < TOK; ++tok) {
    const float* ev = erow[tok];
    float a0 = bb, a1 = 0.f, a2 = 0.f, a3 = 0.f;
    #pragma unroll
    for (int d = 0; d < EMB_D; d += 4) {
      a0 = fmaf(w[d],     ev[d],     a0);
      a1 = fmaf(w[d + 1], ev[d + 1], a1);
      a2 = fmaf(w[d + 2], ev[d + 2], a2);
      a3 = fmaf(w[d + 3], ev[d + 3], a3);
    }
    xw0[(t0 + tok) * G4 + g] = (a0 + a1) + (a2 + a3);
  }
}

// --- fused 2-layer recurrence + classifier head ---
// 128 blocks (one batch row), 512 threads. Thread = (gate g = tid&255,
// half hb = tid>>8); holds 3 half-rows of weights (96 floats -> registers).
// Pipeline: iter t computes layer0 step t AND layer1 step t-1.
__global__ __launch_bounds__(512, 1) void lstm_fused_kernel(
    const float* __restrict__ xw0,
    const float* __restrict__ Whh0, const float* __restrict__ Wih1,
    const float* __restrict__ Whh1, const float* __restrict__ b1c,
    const float* __restrict__ W1, const float* __restrict__ clsb1,
    const float* __restrict__ W2, const float* __restrict__ clsb2,
    float* __restrict__ out) {
  int b = blockIdx.x;
  int tid = threadIdx.x;
  int g = tid & 255;
  int hb = tid >> 8;           // which half of the dot this thread owns

  // 96 weight floats per thread, as float4[8] x3 -> registers
  float4 w0[8], w1[8], w2[8];
  {
    const float4* p0 = (const float4*)(Whh0 + g * HID + hb * 32);
    const float4* p1 = (const float4*)(Wih1 + g * HID + hb * 32);
    const float4* p2 = (const float4*)(Whh1 + g * HID + hb * 32);
    #pragma unroll
    for (int c = 0; c < 8; ++c) { w0[c] = p0[c]; w1[c] = p1[c]; w2[c] = p2[c]; }
  }

  __shared__ float4 h0s4[16];
  __shared__ float4 h1s4[16];
  __shared__ float gp0[512];
  __shared__ float gp1[512];
  __shared__ float zs[HID];
  float* h0f = (float*)h0s4;
  float* h1f = (float*)h1s4;
  if (tid < HID) { h0f[tid] = 0.f; h1f[tid] = 0.f; }
  float c0 = 0.f, c1 = 0.f;
  float bias1 = (hb == 0) ? b1c[g] : 0.f;

  const float* xr = xw0 + (long)b * SEQ * G4;
  float xwA = 0.f, xwB = 0.f;
  if (tid < G4) { xwA = xr[tid]; xwB = xr[G4 + tid]; }
  __syncthreads();

  for (int t = 0; t < SEQ; ++t) {
    int tn = (t + 2 < SEQ) ? (t + 2) : (SEQ - 1);
    float xwC = 0.f;
    if (tid < G4) xwC = xr[(long)tn * G4 + tid];   // distance-2 prefetch

    float a0 = (hb == 0) ? xwA : 0.f, a1 = 0.f, a2 = 0.f, a3 = 0.f;
    float d0 = bias1, d1 = 0.f, d2 = 0.f, d3 = 0.f;
    #pragma unroll
    for (int c = 0; c < 8; ++c) {
      float4 hv = h0s4[hb * 8 + c];
      a0 = fmaf(hv.x, w0[c].x, a0);
      a1 = fmaf(hv.y, w0[c].y, a1);
      a2 = fmaf(hv.z, w0[c].z, a2);
      a3 = fmaf(hv.w, w0[c].w, a3);
      d0 = fmaf(hv.x, w1[c].x, d0);
      d1 = fmaf(hv.y, w1[c].y, d1);
      d2 = fmaf(hv.z, w1[c].z, d2);
      d3 = fmaf(hv.w, w1[c].w, d3);
    }
    #pragma unroll
    for (int c = 0; c < 8; ++c) {
      float4 hv = h1s4[hb * 8 + c];
      d0 = fmaf(hv.x, w2[c].x, d0);
      d1 = fmaf(hv.y, w2[c].y, d1);
      d2 = fmaf(hv.z, w2[c].z, d2);
      d3 = fmaf(hv.w, w2[c].w, d3);
    }
    gp0[tid] = (a0 + a1) + (a2 + a3);
    gp1[tid] = (d0 + d1) + (d2 + d3);
    __syncthreads();
    if (tid < HID) {
      float i_ = gp0[tid]       + gp0[tid + 256];
      float f_ = gp0[tid + 64]  + gp0[tid + 320];
      float gg = gp0[tid + 128] + gp0[tid + 384];
      float o_ = gp0[tid + 192] + gp0[tid + 448];
      c0 = sigf(f_) * c0 + sigf(i_) * tanh_fast(gg);
      h0f[tid] = sigf(o_) * tanh_fast(c0);
    } else if (tid < 2 * HID) {
      if (t > 0) {
        int j = tid - HID;
        float i_ = gp1[j]       + gp1[j + 256];
        float f_ = gp1[j + 64]  + gp1[j + 320];
        float gg = gp1[j + 128] + gp1[j + 384];
        float o_ = gp1[j + 192] + gp1[j + 448];
        c1 = sigf(f_) * c1 + sigf(i_) * tanh_fast(gg);
        h1f[j] = sigf(o_) * tanh_fast(c1);
      }
    }
    __syncthreads();
    xwA = xwB; xwB = xwC;
  }

  // final layer-1 step (t = SEQ-1): h0s holds h0_{1023}, h1s holds h1_{1022}
  {
    float d0 = bias1, d1 = 0.f, d2 = 0.f, d3 = 0.f;
    #pragma unroll
    for (int c = 0; c < 8; ++c) {
      float4 hv = h0s4[hb * 8 + c];
      d0 = fmaf(hv.x, w1[c].x, d0);
      d1 = fmaf(hv.y, w1[c].y, d1);
      d2 = fmaf(hv.z, w1[c].z, d2);
      d3 = fmaf(hv.w, w1[c].w, d3);
    }
    #pragma unroll
    for (int c = 0; c < 8; ++c) {
      float4 hv = h1s4[hb * 8 + c];
      d0 = fmaf(hv.x, w2[c].x, d0);
      d1 = fmaf(hv.y, w2[c].y, d1);
      d2 = fmaf(hv.z, w2[c].z, d2);
      d3 = fmaf(hv.w, w2[c].w, d3);
    }
    gp1[tid] = (d0 + d1) + (d2 + d3);
    __syncthreads();
    if (tid >= HID && tid < 2 * HID) {
      int j = tid - HID;
      float i_ = gp1[j]       + gp1[j + 256];
      float f_ = gp1[j + 64]  + gp1[j + 320];
      float gg = gp1[j + 128] + gp1[j + 384];
      float o_ = gp1[j + 192] + gp1[j + 448];
      c1 = sigf(f_) * c1 + sigf(i_) * tanh_fast(gg);
      h1f[j] = sigf(o_) * tanh_fast(c1);
    }
    __syncthreads();
  }

  // classifier: z = relu(h1 @ W1.T + b1); out = sigmoid(z . W2 + b2)
  if (tid < HID) {
    const float4* w1p = (const float4*)(W1 + tid * HID);
    float z0 = clsb1[tid], z1 = 0.f, z2 = 0.f, z3 = 0.f;
    #pragma unroll
    for (int c = 0; c < 16; ++c) {
      float4 wv = w1p[c];
      float4 hv = h1s4[c];
      z0 = fmaf(hv.x, wv.x, z0);
      z1 = fmaf(hv.y, wv.y, z1);
      z2 = fmaf(hv.z, wv.z, z2);
      z3 = fmaf(hv.w, wv.w, z3);
    }
    float z = (z0 + z1) + (z2 + z3);
    z = fmaxf(z, 0.f);
    zs[tid] = z * W2[tid];
  }
  __syncthreads();
  if (tid == 0) {
    float s = clsb2[0];
    #pragma unroll
    for (int k = 0; k < HID; ++k) s += zs[k];
    out[b] = sigf(s);
  }
}

extern "C" void kernel_launch(void* const* d_in, const int* in_sizes, int n_in,
                              void* d_out, int out_size, void* d_ws, size_t ws_size,
                              hipStream_t stream) {
  const int*   x    = (const int*)d_in[0];
  const float* emb  = (const float*)d_in[1];
  const float* Wih0 = (const float*)d_in[2];
  const float* Whh0 = (const float*)d_in[3];
  const float* bih0 = (const float*)d_in[4];
  const float* bhh0 = (const float*)d_in[5];
  const float* Wih1 = (const float*)d_in[6];
  const float* Whh1 = (const float*)d_in[7];
  const float* bih1 = (const float*)d_in[8];
  const float* bhh1 = (const float*)d_in[9];
  const float* W1   = (const float*)d_in[10];
  const float* b1   = (const float*)d_in[11];
  const float* W2   = (const float*)d_in[12];
  const float* b2   = (const float*)d_in[13];
  float* out = (float*)d_out;

  char* ws = (char*)d_ws;
  const size_t XW0_BYTES = (size_t)BATCH * SEQ * G4 * sizeof(float);  // 134217728
  float* xw0   = (float*)ws;
  float* Wih0T = (float*)(ws + XW0_BYTES);
  float* b0c   = (float*)(ws + XW0_BYTES + EMB_D * G4 * sizeof(float));
  float* b1c   = (float*)(ws + XW0_BYTES + EMB_D * G4 * sizeof(float) + G4 * sizeof(float));

  prep_kernel<<<1, 256, 0, stream>>>(Wih0, bih0, bhh0, bih1, bhh1, Wih0T, b0c, b1c);
  xw0_kernel<<<(BATCH * SEQ) / TOK, 256, 0, stream>>>(x, emb, Wih0T, b0c, xw0);
  lstm_fused_kernel<<<BATCH, 512, 0, stream>>>(xw0, Whh0, Wih1, Whh1, b1c,
                                               W1, b1, W2, b2, out);
}